// Round 6
// baseline (636.791 us; speedup 1.0000x reference)
//
#include <hip/hip_runtime.h>
#include <hip/hip_bf16.h>
#include <stdint.h>

#define STATE 512
#define PROJ 300
#define PPAD 320
#define BATSEQ 320
#define TE 327680            // 320*1024 edges
#define TILES_PER_BLOCK 40
#define EDGE_BLOCKS 256

typedef __bf16 bf16x8 __attribute__((ext_vector_type(8)));
typedef float f32x4 __attribute__((ext_vector_type(4)));
typedef unsigned int u32x4 __attribute__((ext_vector_type(4)));

__device__ inline unsigned short f2bf(float x) {
  unsigned u = __builtin_bit_cast(unsigned, x);
  unsigned r = u + 0x7fffu + ((u >> 16) & 1u);   // round-to-nearest-even
  return (unsigned short)(r >> 16);
}

__device__ inline unsigned cvt_pk_bf16(float lo, float hi) {
  unsigned r;
  asm("v_cvt_pk_bf16_f32 %0, %1, %2" : "=v"(r) : "v"(lo), "v"(hi));
  return r;
}

// ---------------- prep: pack W1/W2/W3 into MFMA B-fragment layout (bf16, P padded to 320),
// and pad biases to 320 floats ----------------
__global__ __launch_bounds__(256) void prep_kernel(
    const float* __restrict__ W1, const float* __restrict__ b1,
    const float* __restrict__ W2, const float* __restrict__ b2,
    const float* __restrict__ W3, const float* __restrict__ b3,
    unsigned short* __restrict__ w1p, unsigned short* __restrict__ w2p,
    unsigned short* __restrict__ w3p,
    float* __restrict__ b1p, float* __restrict__ b2p, float* __restrict__ b3p)
{
  int idx = blockIdx.x * 256 + threadIdx.x;
  const int WN = PPAD * STATE;                    // 163840
  if (idx < 3 * WN) {
    int which = idx / WN, r = idx % WN;
    int cs = r / 512, q = r % 512;                // cs = c*16+s
    int lane = q / 8, i = q % 8;
    int c = cs / 16, s = cs % 16;
    int p = c * 16 + (lane & 15);
    int k = s * 32 + (lane >> 4) * 8 + i;
    const float* W = (which == 0) ? W1 : ((which == 1) ? W2 : W3);
    unsigned short* dst = (which == 0) ? w1p : ((which == 1) ? w2p : w3p);
    float v = (p < PROJ) ? W[(size_t)p * STATE + k] : 0.0f;
    dst[r] = f2bf(v);
  } else if (idx < 3 * WN + 3 * PPAD) {
    int r = idx - 3 * WN;
    int which = r / PPAD, p = r % PPAD;
    const float* B = (which == 0) ? b1 : ((which == 1) ? b2 : b3);
    float* dst = (which == 0) ? b1p : ((which == 1) ? b2p : b3p);
    dst[p] = (p < PROJ) ? B[p] : 0.0f;
  }
}

// ---------------- node kernel: one block per b. Computes f1 = W1*n + b1 and
// f3' = W3*n + b3 - b2, writes both as f32 tables [b][row][320], and the
// closed-form  T_b = 32*sum(f1^2 + f3'^2) - 2*sum_p (sum_j f3')(sum_i f1). ----------------
__global__ __launch_bounds__(256, 2) void node_kernel(
    const float* __restrict__ nodes,
    const unsigned short* __restrict__ w1p, const unsigned short* __restrict__ w3p,
    const float* __restrict__ b1p, const float* __restrict__ b2p,
    const float* __restrict__ b3p,
    float* __restrict__ f1t, float* __restrict__ f3t,
    double* __restrict__ pnode)
{
  __shared__ __align__(16) unsigned short tile[32 * 512];   // 32 KiB
  __shared__ float G1[PPAD], G3[PPAD];
  __shared__ double red[4];
  const int tid = threadIdx.x;
  const int wave = tid >> 6, lane = tid & 63;
  const int b = blockIdx.x;
  const float* src = nodes + (size_t)b * 32 * STATE;

  for (int t = tid; t < PPAD; t += 256) { G1[t] = 0.f; G3[t] = 0.f; }

  // stage 32x512 f32 -> bf16 LDS, swizzle: byte ^= (row&7)<<4
  #pragma unroll
  for (int m = 0; m < 16; ++m) {
    int k = wave + 4 * m;
    int row = k >> 1;
    int fc = (k & 1) * 64 + lane;
    f32x4 v = *(const f32x4*)(src + row * STATE + fc * 4);
    unsigned lo = f2bf(v.x) | ((unsigned)f2bf(v.y) << 16);
    unsigned hi = f2bf(v.z) | ((unsigned)f2bf(v.w) << 16);
    unsigned long long pk = (unsigned long long)lo | ((unsigned long long)hi << 32);
    unsigned off = (unsigned)(row * 1024 + fc * 8) ^ (unsigned)((row & 7) << 4);
    *(unsigned long long*)((char*)tile + off) = pk;
  }
  __syncthreads();

  const int lrow = lane & 15, lk = lane >> 4;
  const int cbase = wave * 5;

  f32x4 af1[2][5], af3[2][5];
  #pragma unroll
  for (int rg = 0; rg < 2; ++rg)
    #pragma unroll
    for (int c = 0; c < 5; ++c) {
      af1[rg][c][0]=0.f; af1[rg][c][1]=0.f; af1[rg][c][2]=0.f; af1[rg][c][3]=0.f;
      af3[rg][c][0]=0.f; af3[rg][c][1]=0.f; af3[rg][c][2]=0.f; af3[rg][c][3]=0.f;
    }
  for (int s = 0; s < 16; ++s) {
    bf16x8 a[2];
    #pragma unroll
    for (int rg = 0; rg < 2; ++rg) {
      int row = rg * 16 + lrow;
      unsigned off = (unsigned)(row * 1024 + s * 64 + lk * 16) ^ (unsigned)((row & 7) << 4);
      a[rg] = *(const bf16x8*)((const char*)tile + off);
    }
    #pragma unroll
    for (int c = 0; c < 5; ++c) {
      size_t fo = ((size_t)(((cbase + c) * 16 + s) * 64 + lane)) * 8;
      bf16x8 bf1 = *(const bf16x8*)(w1p + fo);
      bf16x8 bf3 = *(const bf16x8*)(w3p + fo);
      #pragma unroll
      for (int rg = 0; rg < 2; ++rg) {
        af1[rg][c] = __builtin_amdgcn_mfma_f32_16x16x32_bf16(a[rg], bf1, af1[rg][c], 0, 0, 0);
        af3[rg][c] = __builtin_amdgcn_mfma_f32_16x16x32_bf16(a[rg], bf3, af3[rg][c], 0, 0, 0);
      }
    }
  }

  float sq = 0.f;
  #pragma unroll
  for (int rg = 0; rg < 2; ++rg)
    #pragma unroll
    for (int c = 0; c < 5; ++c) {
      int p = (cbase + c) * 16 + lrow;
      float bb1 = b1p[p], bb2 = b2p[p], bb3 = b3p[p];
      #pragma unroll
      for (int r = 0; r < 4; ++r) {
        int m = rg * 16 + lk * 4 + r;           // C/D row
        float v1 = af1[rg][c][r] + bb1;
        float v3 = af3[rg][c][r] + bb3 - bb2;
        f1t[((size_t)b * 32 + m) * PPAD + p] = v1;
        f3t[((size_t)b * 32 + m) * PPAD + p] = v3;
        sq += v1 * v1 + v3 * v3;
        atomicAdd(&G1[p], v1);
        atomicAdd(&G3[p], v3);
      }
    }
  __syncthreads();

  float s7 = 0.f;
  for (int t = tid; t < PPAD; t += 256) s7 += G3[t] * G1[t];

  float val = 32.f * sq - 2.f * s7;
  #pragma unroll
  for (int m = 32; m >= 1; m >>= 1) val += __shfl_xor(val, m, 64);
  if (lane == 0) red[wave] = (double)val;
  __syncthreads();
  if (tid == 0) pnode[b] = red[0] + red[1] + red[2] + red[3];
}

// ---------------- edge kernel: PERSISTENT, 1 block/CU, 40 tiles of 32 rows each.
// Double-buffered async DMA staging (global_load_lds, counted vmcnt, raw s_barrier)
// so one tile's 64KB is always in flight while the previous computes.
// W2 (this wave's 80-col slice) pinned in registers for the whole kernel.
// Per tile: F2 = W2*e via MFMA (f32->bf16 at fragment read), epilogue contracts
// against f3'[b,j,p] (L2) and f1[b,i,p]; accumulates ss - 2*cr per thread. ----------------
__global__ __launch_bounds__(256, 1) void edge_kernel(
    const float* __restrict__ edges, const unsigned short* __restrict__ w2p,
    const float* __restrict__ f1t, const float* __restrict__ f3t,
    double* __restrict__ pedge)
{
  __shared__ __align__(16) float bufs[2][32 * 512];   // 2 x 64 KiB f32, XOR-swizzled content
  __shared__ double redd[4];
  const int tid = threadIdx.x;
  const int wave = tid >> 6, lane = tid & 63;
  const int lrow = lane & 15, lk = lane >> 4;
  const int cb = wave * 5;

  // ---- pin this wave's W2 column slice (80 cols x K=512) in registers: 320 VGPRs
  bf16x8 w2r[5][16];
  #pragma unroll
  for (int c = 0; c < 5; ++c)
    #pragma unroll
    for (int s = 0; s < 16; ++s)
      w2r[c][s] = *(const bf16x8*)(w2p + ((size_t)(((cb + c) * 16 + s) * 64 + lane)) * 8);

  const int t0 = blockIdx.x * TILES_PER_BLOCK;

  // DMA one 32x512 f32 tile into bufs[bsel]; wave w fills rows 8w..8w+7.
  // LDS dest linear; global SOURCE pre-swizzled so element (row,d) lands at
  // byte row*2048 + ((d*4) ^ ((row&7)<<4)).  16 loads per wave per tile.
  auto issue = [&](int tt, int bsel) {
    const char* src = (const char*)(edges + (size_t)(t0 + tt) * 32 * STATE);
    char* ldsw = (char*)(&bufs[bsel][0]) + wave * 16384;
    #pragma unroll
    for (int t = 0; t < 16; ++t) {
      int o = wave * 16384 + t * 1024 + lane * 16;   // linear dest offset of THIS lane
      int row = o >> 11;
      int cl = o & 2047;
      int srcoff = row * 2048 + (cl ^ ((row & 7) << 4));
      __builtin_amdgcn_global_load_lds(
          (const __attribute__((address_space(1))) unsigned int*)(src + srcoff),
          (__attribute__((address_space(3))) unsigned int*)(ldsw + t * 1024),
          16, 0, 0);
    }
  };

  issue(0, 0);
  issue(1, 1);

  double dval = 0.0;

  for (int tt = 0; tt < TILES_PER_BLOCK; ++tt) {
    // wait for tile tt's 16 DMA loads (tile tt+1's 16 remain in flight)
    if (tt < TILES_PER_BLOCK - 1) asm volatile("s_waitcnt vmcnt(16)" ::: "memory");
    else                          asm volatile("s_waitcnt vmcnt(0)"  ::: "memory");
    __builtin_amdgcn_s_barrier();
    __builtin_amdgcn_sched_barrier(0);

    const float* tilep = &bufs[tt & 1][0];
    const int gt = t0 + tt;
    const int b = gt >> 5, i = gt & 31;

    f32x4 acc[2][5];
    #pragma unroll
    for (int rg = 0; rg < 2; ++rg)
      #pragma unroll
      for (int c = 0; c < 5; ++c) { acc[rg][c][0]=0.f; acc[rg][c][1]=0.f; acc[rg][c][2]=0.f; acc[rg][c][3]=0.f; }

    #pragma unroll
    for (int s = 0; s < 16; ++s) {
      bf16x8 a[2];
      #pragma unroll
      for (int rg = 0; rg < 2; ++rg) {
        int row = rg * 16 + lrow;
        int sw = (row & 7) << 4;
        const char* base = (const char*)tilep + row * 2048;
        f32x4 lo = *(const f32x4*)(base + ((s * 128 + lk * 32) ^ sw));
        f32x4 hi = *(const f32x4*)(base + ((s * 128 + lk * 32 + 16) ^ sw));
        u32x4 pk;
        pk[0] = cvt_pk_bf16(lo[0], lo[1]);
        pk[1] = cvt_pk_bf16(lo[2], lo[3]);
        pk[2] = cvt_pk_bf16(hi[0], hi[1]);
        pk[3] = cvt_pk_bf16(hi[2], hi[3]);
        a[rg] = __builtin_bit_cast(bf16x8, pk);
      }
      #pragma unroll
      for (int c = 0; c < 5; ++c)
        #pragma unroll
        for (int rg = 0; rg < 2; ++rg)
          acc[rg][c] = __builtin_amdgcn_mfma_f32_16x16x32_bf16(a[rg], w2r[c][s], acc[rg][c], 0, 0, 0);
    }

    // epilogue: ss = sum F2^2 ; cr = sum (f3'[j,p] - f1[i,p]) * F2
    const float* f1b = f1t + ((size_t)b * 32 + i) * PPAD;
    const float* f3b = f3t + (size_t)b * 32 * PPAD;
    float f1v[5];
    #pragma unroll
    for (int c = 0; c < 5; ++c) f1v[c] = f1b[(cb + c) * 16 + lrow];

    float ss = 0.f, cr = 0.f;
    #pragma unroll
    for (int rg = 0; rg < 2; ++rg)
      #pragma unroll
      for (int c = 0; c < 5; ++c) {
        int p = (cb + c) * 16 + lrow;
        #pragma unroll
        for (int r = 0; r < 4; ++r) {
          int j = rg * 16 + lk * 4 + r;
          float F2 = acc[rg][c][r];
          float t = f3b[(size_t)j * PPAD + p] - f1v[c];
          ss += F2 * F2;
          cr += t * F2;
        }
      }
    dval += (double)ss - 2.0 * (double)cr;

    __builtin_amdgcn_sched_barrier(0);
    __builtin_amdgcn_s_barrier();     // all waves done reading bufs[tt&1]
    if (tt + 2 < TILES_PER_BLOCK) issue(tt + 2, tt & 1);
  }

  #pragma unroll
  for (int m = 32; m >= 1; m >>= 1) dval += __shfl_xor(dval, m, 64);
  if (lane == 0) redd[wave] = dval;
  __syncthreads();
  if (tid == 0) pedge[blockIdx.x] = redd[0] + redd[1] + redd[2] + redd[3];
}

// ---------------- final combine ----------------
__global__ __launch_bounds__(256) void final_kernel(
    const double* __restrict__ pedge, const double* __restrict__ pnode,
    const int* __restrict__ seqp, float* __restrict__ out)
{
  __shared__ double red[4];
  const int tid = threadIdx.x, wave = tid >> 6, lane = tid & 63;
  double v = 0.0;
  for (int t = tid; t < EDGE_BLOCKS; t += 256) v += pedge[t];
  for (int t = tid; t < 320; t += 256) v += pnode[t];
  #pragma unroll
  for (int m = 32; m >= 1; m >>= 1) v += __shfl_xor(v, m, 64);
  if (lane == 0) red[wave] = v;
  __syncthreads();
  if (tid == 0) {
    double Total = red[0] + red[1] + red[2] + red[3];
    int seq = seqp[0];
    int batch = (seq > 0) ? (BATSEQ / seq) : 1;
    out[0] = (float)(Total / ((double)BATSEQ * (double)PROJ) / (double)batch);
  }
}

extern "C" void kernel_launch(void* const* d_in, const int* in_sizes, int n_in,
                              void* d_out, int out_size, void* d_ws, size_t ws_size,
                              hipStream_t stream)
{
  const float* nodes = (const float*)d_in[0];
  const float* edges = (const float*)d_in[1];
  const int*   seqp  = (const int*)d_in[4];
  const float* W1 = (const float*)d_in[5];
  const float* b1 = (const float*)d_in[6];
  const float* W2 = (const float*)d_in[7];
  const float* b2 = (const float*)d_in[8];
  const float* W3 = (const float*)d_in[9];
  const float* b3 = (const float*)d_in[10];

  char* ws = (char*)d_ws;
  unsigned short* w1p = (unsigned short*)(ws + 0);
  unsigned short* w3p = (unsigned short*)(ws + 327680);
  unsigned short* w2p = (unsigned short*)(ws + 655360);
  float* b1p = (float*)(ws + 983040);
  float* b2p = (float*)(ws + 984320);
  float* b3p = (float*)(ws + 985600);
  float* f1t = (float*)(ws + 1048576);            // 13,107,200 B
  float* f3t = (float*)(ws + 14155776);           // 13,107,200 B
  double* pedge = (double*)(ws + 27262976);       // 256 doubles
  double* pnode = (double*)(ws + 27344896);       // 320 doubles

  prep_kernel<<<1925, 256, 0, stream>>>(W1, b1, W2, b2, W3, b3,
                                        w1p, w2p, w3p, b1p, b2p, b3p);
  node_kernel<<<320, 256, 0, stream>>>(nodes, w1p, w3p, b1p, b2p, b3p,
                                       f1t, f3t, pnode);
  edge_kernel<<<EDGE_BLOCKS, 256, 0, stream>>>(edges, w2p, f1t, f3t, pedge);
  final_kernel<<<1, 256, 0, stream>>>(pedge, pnode, seqp, (float*)d_out);
}

// Round 7
// 353.320 us; speedup vs baseline: 1.8023x; 1.8023x over previous
//
#include <hip/hip_runtime.h>
#include <hip/hip_bf16.h>
#include <stdint.h>

#define STATE 512
#define PROJ 300
#define PPAD 320
#define BATSEQ 320
#define TE 327680            // 320*1024 edges
#define PSTR 328             // t2 tile stride (ushort) — spreads banks, keeps 16B align

typedef __bf16 bf16x8 __attribute__((ext_vector_type(8)));
typedef float f32x4 __attribute__((ext_vector_type(4)));

__device__ inline unsigned short f2bf(float x) {
  unsigned u = __builtin_bit_cast(unsigned, x);
  unsigned r = u + 0x7fffu + ((u >> 16) & 1u);   // round-to-nearest-even
  return (unsigned short)(r >> 16);
}

// ---------------- prep: pack W1/W2/W3 into MFMA B-fragment layout (bf16, P padded to 320),
// plus W2-transposed pack (B[n=state][k=p], 512 cols x 320 K) and padded biases ----------------
__global__ __launch_bounds__(256) void prep_kernel(
    const float* __restrict__ W1, const float* __restrict__ b1,
    const float* __restrict__ W2, const float* __restrict__ b2,
    const float* __restrict__ W3, const float* __restrict__ b3,
    unsigned short* __restrict__ w1p, unsigned short* __restrict__ w2p,
    unsigned short* __restrict__ w3p, unsigned short* __restrict__ w2tp,
    float* __restrict__ b1p, float* __restrict__ b2p, float* __restrict__ b3p)
{
  int idx = blockIdx.x * 256 + threadIdx.x;
  const int WN = PPAD * STATE;                    // 163840
  if (idx < 3 * WN) {
    int which = idx / WN, r = idx % WN;
    int cs = r / 512, q = r % 512;                // cs = c*16+s
    int lane = q / 8, i = q % 8;
    int c = cs / 16, s = cs % 16;
    int p = c * 16 + (lane & 15);
    int k = s * 32 + (lane >> 4) * 8 + i;
    const float* W = (which == 0) ? W1 : ((which == 1) ? W2 : W3);
    unsigned short* dst = (which == 0) ? w1p : ((which == 1) ? w2p : w3p);
    float v = (p < PROJ) ? W[(size_t)p * STATE + k] : 0.0f;
    dst[r] = f2bf(v);
  } else if (idx < 4 * WN) {
    // w2tp: B-fragment for g-GEMM. value = W2[p][n], p = contraction (320, 10 s-steps),
    // n = state (512, 32 col-tiles). r = ((ct*10+s2)*64+lane)*8 + ii
    int r = idx - 3 * WN;
    int cs = r / 512, q = r % 512;
    int lane = q / 8, ii = q % 8;
    int ct = cs / 10, s2 = cs % 10;
    int p = s2 * 32 + (lane >> 4) * 8 + ii;
    int n = ct * 16 + (lane & 15);
    float v = (p < PROJ) ? W2[(size_t)p * STATE + n] : 0.0f;
    w2tp[r] = f2bf(v);
  } else if (idx < 4 * WN + 3 * PPAD) {
    int r = idx - 4 * WN;
    int which = r / PPAD, p = r % PPAD;
    const float* B = (which == 0) ? b1 : ((which == 1) ? b2 : b3);
    float* dst = (which == 0) ? b1p : ((which == 1) ? b2p : b3p);
    dst[p] = (p < PROJ) ? B[p] : 0.0f;
  }
}

// ---------------- node kernel: one block per b.
// Phase A: f1 = W1*n + b1, f3' = W3*n + b3 - b2 (MFMA), closed-form
//   T_b = 32*sum(f1^2 + f3'^2) - 2*sum_p (sum_j f3')(sum_i f1)  -> pnode[b]
// Phase B: g1 = W2^T f1, g3 = W2^T f3' (MFMA via LDS bf16 tiles) -> f32 tables [b][32][512]
__global__ __launch_bounds__(256, 2) void node_kernel(
    const float* __restrict__ nodes,
    const unsigned short* __restrict__ w1p, const unsigned short* __restrict__ w3p,
    const unsigned short* __restrict__ w2tp,
    const float* __restrict__ b1p, const float* __restrict__ b2p,
    const float* __restrict__ b3p,
    float* __restrict__ g1t, float* __restrict__ g3t,
    double* __restrict__ pnode)
{
  __shared__ __align__(16) unsigned short tile[32 * 512];   // 32 KiB
  __shared__ __align__(16) unsigned short t2a[32 * PSTR];   // 20.5 KiB (f1, bf16)
  __shared__ __align__(16) unsigned short t2b[32 * PSTR];   // 20.5 KiB (f3', bf16)
  __shared__ float G1[PPAD], G3[PPAD];
  __shared__ double red[4];
  const int tid = threadIdx.x;
  const int wave = tid >> 6, lane = tid & 63;
  const int b = blockIdx.x;
  const float* src = nodes + (size_t)b * 32 * STATE;

  for (int t = tid; t < PPAD; t += 256) { G1[t] = 0.f; G3[t] = 0.f; }

  // stage 32x512 f32 -> bf16 LDS, swizzle: byte ^= (row&7)<<4
  #pragma unroll
  for (int m = 0; m < 16; ++m) {
    int k = wave + 4 * m;
    int row = k >> 1;
    int fc = (k & 1) * 64 + lane;
    f32x4 v = *(const f32x4*)(src + row * STATE + fc * 4);
    unsigned lo = f2bf(v.x) | ((unsigned)f2bf(v.y) << 16);
    unsigned hi = f2bf(v.z) | ((unsigned)f2bf(v.w) << 16);
    unsigned long long pk = (unsigned long long)lo | ((unsigned long long)hi << 32);
    unsigned off = (unsigned)(row * 1024 + fc * 8) ^ (unsigned)((row & 7) << 4);
    *(unsigned long long*)((char*)tile + off) = pk;
  }
  __syncthreads();

  const int lrow = lane & 15, lk = lane >> 4;
  const int cbase = wave * 5;

  f32x4 af1[2][5], af3[2][5];
  #pragma unroll
  for (int rg = 0; rg < 2; ++rg)
    #pragma unroll
    for (int c = 0; c < 5; ++c) {
      af1[rg][c][0]=0.f; af1[rg][c][1]=0.f; af1[rg][c][2]=0.f; af1[rg][c][3]=0.f;
      af3[rg][c][0]=0.f; af3[rg][c][1]=0.f; af3[rg][c][2]=0.f; af3[rg][c][3]=0.f;
    }
  for (int s = 0; s < 16; ++s) {
    bf16x8 a[2];
    #pragma unroll
    for (int rg = 0; rg < 2; ++rg) {
      int row = rg * 16 + lrow;
      unsigned off = (unsigned)(row * 1024 + s * 64 + lk * 16) ^ (unsigned)((row & 7) << 4);
      a[rg] = *(const bf16x8*)((const char*)tile + off);
    }
    #pragma unroll
    for (int c = 0; c < 5; ++c) {
      size_t fo = ((size_t)(((cbase + c) * 16 + s) * 64 + lane)) * 8;
      bf16x8 bf1 = *(const bf16x8*)(w1p + fo);
      bf16x8 bf3 = *(const bf16x8*)(w3p + fo);
      #pragma unroll
      for (int rg = 0; rg < 2; ++rg) {
        af1[rg][c] = __builtin_amdgcn_mfma_f32_16x16x32_bf16(a[rg], bf1, af1[rg][c], 0, 0, 0);
        af3[rg][c] = __builtin_amdgcn_mfma_f32_16x16x32_bf16(a[rg], bf3, af3[rg][c], 0, 0, 0);
      }
    }
  }

  float sq = 0.f;
  #pragma unroll
  for (int rg = 0; rg < 2; ++rg)
    #pragma unroll
    for (int c = 0; c < 5; ++c) {
      int p = (cbase + c) * 16 + lrow;
      float bb1 = b1p[p], bb2 = b2p[p], bb3 = b3p[p];
      #pragma unroll
      for (int r = 0; r < 4; ++r) {
        int m = rg * 16 + lk * 4 + r;           // C/D row
        float v1 = af1[rg][c][r] + bb1;
        float v3 = af3[rg][c][r] + bb3 - bb2;
        t2a[m * PSTR + p] = f2bf(v1);
        t2b[m * PSTR + p] = f2bf(v3);
        sq += v1 * v1 + v3 * v3;
        atomicAdd(&G1[p], v1);
        atomicAdd(&G3[p], v3);
      }
    }
  __syncthreads();

  float s7 = 0.f;
  for (int t = tid; t < PPAD; t += 256) s7 += G3[t] * G1[t];
  float val = 32.f * sq - 2.f * s7;
  #pragma unroll
  for (int m = 32; m >= 1; m >>= 1) val += __shfl_xor(val, m, 64);
  if (lane == 0) red[wave] = (double)val;

  // ---- Phase B: g = W2^T f, two passes (f1 -> g1t, f3' -> g3t) ----
  for (int pass = 0; pass < 2; ++pass) {
    const unsigned short* t2 = pass ? t2b : t2a;
    float* gt = pass ? g3t : g1t;
    f32x4 acc2[2][8];
    #pragma unroll
    for (int rg = 0; rg < 2; ++rg)
      #pragma unroll
      for (int cc = 0; cc < 8; ++cc) { acc2[rg][cc][0]=0.f; acc2[rg][cc][1]=0.f; acc2[rg][cc][2]=0.f; acc2[rg][cc][3]=0.f; }
    for (int s2 = 0; s2 < 10; ++s2) {
      bf16x8 a[2];
      #pragma unroll
      for (int rg = 0; rg < 2; ++rg) {
        int mrow = rg * 16 + lrow;
        a[rg] = *(const bf16x8*)(t2 + mrow * PSTR + s2 * 32 + lk * 8);
      }
      #pragma unroll
      for (int cc = 0; cc < 8; ++cc) {
        int ct = wave * 8 + cc;
        bf16x8 bfr = *(const bf16x8*)(w2tp + ((size_t)((ct * 10 + s2) * 64 + lane)) * 8);
        #pragma unroll
        for (int rg = 0; rg < 2; ++rg)
          acc2[rg][cc] = __builtin_amdgcn_mfma_f32_16x16x32_bf16(a[rg], bfr, acc2[rg][cc], 0, 0, 0);
      }
    }
    #pragma unroll
    for (int rg = 0; rg < 2; ++rg)
      #pragma unroll
      for (int cc = 0; cc < 8; ++cc) {
        int n = (wave * 8 + cc) * 16 + lrow;
        #pragma unroll
        for (int r = 0; r < 4; ++r) {
          int mm = rg * 16 + lk * 4 + r;
          gt[((size_t)b * 32 + mm) * STATE + n] = acc2[rg][cc][r];
        }
      }
  }

  __syncthreads();
  if (tid == 0) pnode[b] = red[0] + red[1] + red[2] + red[3];
}

// ---------------- edge kernel: block = (b, i-pair), 64 contiguous rows, 256 threads.
// Staging loop streams edges once (f32->bf16 LDS) and folds the j-part of the
// cross term (e . g3[b,j]) in f32; the i-part uses per-thread edge row-sums
// (sE0/sE1, d-slice is loop-invariant per thread) dotted with g1[i0],g1[i1]
// AFTER the loop — removes one load stream from the hot loop.
// MFMA phase: pure sum((W2 e)^2); wave w owns col group w (5 cols) x all 64 rows.
// Emits one double per block: ss - 2*cr. ----------------
__global__ __launch_bounds__(256, 2) void edge_kernel(
    const float* __restrict__ edges, const unsigned short* __restrict__ w2p,
    const float* __restrict__ g1t, const float* __restrict__ g3t,
    double* __restrict__ pedge)
{
  __shared__ __align__(16) unsigned short tile[64 * 512];   // 64 KiB
  __shared__ double redd[4][2];
  const int tid = threadIdx.x;
  const int wave = tid >> 6, lane = tid & 63;

  // XCD-chunked swizzle: all 16 blocks of one b land on one XCD (5120 % 8 == 0)
  const int orig = blockIdx.x;
  const int wg = (orig & 7) * 640 + (orig >> 3);
  const int b = wg >> 4, q = wg & 15;          // rows q*64..q*64+63, i-pair {2q, 2q+1}
  const float* src = edges + ((size_t)b * 1024 + (size_t)q * 64) * STATE;
  const float* g3b = g3t + (size_t)b * 32 * STATE;
  const float* g1b = g1t + ((size_t)b * 32 + (size_t)q * 2) * STATE;

  // stage 64x512 f32 -> bf16 LDS (XOR swizzle) + cross-term j-part dot.
  // Thread's d-slice fc = tid & 127 is LOOP-INVARIANT (256 = 2*128); row = 2m + (tid>>7).
  float cr = 0.f;
  f32x4 sE0 = {0.f, 0.f, 0.f, 0.f}, sE1 = {0.f, 0.f, 0.f, 0.f};
  const int fc = tid & 127;
  const int rhi = tid >> 7;
  #pragma unroll 16
  for (int m = 0; m < 32; ++m) {
    int row = 2 * m + rhi;                      // 0..63
    f32x4 e  = *(const f32x4*)(src + row * STATE + fc * 4);
    f32x4 g3 = *(const f32x4*)(g3b + (row & 31) * STATE + fc * 4);
    cr += e.x * g3.x + e.y * g3.y + e.z * g3.z + e.w * g3.w;
    if (m < 16) sE0 += e; else sE1 += e;        // rows<32 -> i0, rows>=32 -> i1
    unsigned lo = f2bf(e.x) | ((unsigned)f2bf(e.y) << 16);
    unsigned hi = f2bf(e.z) | ((unsigned)f2bf(e.w) << 16);
    unsigned long long pk = (unsigned long long)lo | ((unsigned long long)hi << 32);
    unsigned off = (unsigned)(row * 1024 + fc * 8) ^ (unsigned)((row & 7) << 4);
    *(unsigned long long*)((char*)tile + off) = pk;
  }
  {
    f32x4 g1a = *(const f32x4*)(g1b + fc * 4);            // g1[i0]
    f32x4 g1c = *(const f32x4*)(g1b + STATE + fc * 4);    // g1[i1]
    cr -= sE0.x * g1a.x + sE0.y * g1a.y + sE0.z * g1a.z + sE0.w * g1a.w;
    cr -= sE1.x * g1c.x + sE1.y * g1c.y + sE1.z * g1c.z + sE1.w * g1c.w;
  }
  __syncthreads();

  // MFMA: 64 rows x 320 cols. wave owns cols wave*80..+80, all 64 rows.
  const int lrow = lane & 15, lk = lane >> 4;
  const int cb = wave * 5;
  f32x4 acc[4][5];
  #pragma unroll
  for (int rg = 0; rg < 4; ++rg)
    #pragma unroll
    for (int c = 0; c < 5; ++c) { acc[rg][c][0]=0.f; acc[rg][c][1]=0.f; acc[rg][c][2]=0.f; acc[rg][c][3]=0.f; }
  for (int s = 0; s < 16; ++s) {
    bf16x8 a[4];
    #pragma unroll
    for (int rg = 0; rg < 4; ++rg) {
      int row = rg * 16 + lrow;
      unsigned off = (unsigned)(row * 1024 + s * 64 + lk * 16) ^ (unsigned)((row & 7) << 4);
      a[rg] = *(const bf16x8*)((const char*)tile + off);
    }
    #pragma unroll
    for (int c = 0; c < 5; ++c) {
      bf16x8 bfr = *(const bf16x8*)(w2p + ((size_t)(((cb + c) * 16 + s) * 64 + lane)) * 8);
      #pragma unroll
      for (int rg = 0; rg < 4; ++rg)
        acc[rg][c] = __builtin_amdgcn_mfma_f32_16x16x32_bf16(a[rg], bfr, acc[rg][c], 0, 0, 0);
    }
  }

  float ss = 0.f;
  #pragma unroll
  for (int rg = 0; rg < 4; ++rg)
    #pragma unroll
    for (int c = 0; c < 5; ++c)
      #pragma unroll
      for (int r = 0; r < 4; ++r) ss += acc[rg][c][r] * acc[rg][c][r];

  #pragma unroll
  for (int m = 32; m >= 1; m >>= 1) {
    ss += __shfl_xor(ss, m, 64);
    cr += __shfl_xor(cr, m, 64);
  }
  if (lane == 0) { redd[wave][0] = (double)ss; redd[wave][1] = (double)cr; }
  __syncthreads();
  if (tid == 0) {
    double sT = 0.0, cT = 0.0;
    #pragma unroll
    for (int w = 0; w < 4; ++w) { sT += redd[w][0]; cT += redd[w][1]; }
    pedge[wg] = sT - 2.0 * cT;
  }
}

// ---------------- final combine ----------------
__global__ __launch_bounds__(256) void final_kernel(
    const double* __restrict__ pedge, const double* __restrict__ pnode,
    const int* __restrict__ seqp, float* __restrict__ out)
{
  __shared__ double red[4];
  const int tid = threadIdx.x, wave = tid >> 6, lane = tid & 63;
  double v = 0.0;
  for (int t = tid; t < 5120; t += 256) v += pedge[t];
  for (int t = tid; t < 320; t += 256) v += pnode[t];
  #pragma unroll
  for (int m = 32; m >= 1; m >>= 1) v += __shfl_xor(v, m, 64);
  if (lane == 0) red[wave] = v;
  __syncthreads();
  if (tid == 0) {
    double Total = red[0] + red[1] + red[2] + red[3];
    int seq = seqp[0];
    int batch = (seq > 0) ? (BATSEQ / seq) : 1;
    out[0] = (float)(Total / ((double)BATSEQ * (double)PROJ) / (double)batch);
  }
}

extern "C" void kernel_launch(void* const* d_in, const int* in_sizes, int n_in,
                              void* d_out, int out_size, void* d_ws, size_t ws_size,
                              hipStream_t stream)
{
  const float* nodes = (const float*)d_in[0];
  const float* edges = (const float*)d_in[1];
  const int*   seqp  = (const int*)d_in[4];
  const float* W1 = (const float*)d_in[5];
  const float* b1 = (const float*)d_in[6];
  const float* W2 = (const float*)d_in[7];
  const float* b2 = (const float*)d_in[8];
  const float* W3 = (const float*)d_in[9];
  const float* b3 = (const float*)d_in[10];

  char* ws = (char*)d_ws;
  unsigned short* w1p  = (unsigned short*)(ws + 0);
  unsigned short* w3p  = (unsigned short*)(ws + 327680);
  unsigned short* w2p  = (unsigned short*)(ws + 655360);
  unsigned short* w2tp = (unsigned short*)(ws + 983040);
  float* b1p = (float*)(ws + 1310720);
  float* b2p = (float*)(ws + 1312000);
  float* b3p = (float*)(ws + 1313280);
  float* g1t = (float*)(ws + 2097152);            // 20,971,520 B
  float* g3t = (float*)(ws + 23068672);           // 20,971,520 B
  double* pedge = (double*)(ws + 44040192);       // 5120 doubles
  double* pnode = (double*)(ws + 44081152);       // 320 doubles

  prep_kernel<<<2564, 256, 0, stream>>>(W1, b1, W2, b2, W3, b3,
                                        w1p, w2p, w3p, w2tp, b1p, b2p, b3p);
  node_kernel<<<320, 256, 0, stream>>>(nodes, w1p, w3p, w2tp, b1p, b2p, b3p,
                                       g1t, g3t, pnode);
  edge_kernel<<<5120, 256, 0, stream>>>(edges, w2p, g1t, g3t, pedge);
  final_kernel<<<1, 256, 0, stream>>>(pedge, pnode, seqp, (float*)d_out);
}